// Round 1
// baseline (6588.692 us; speedup 1.0000x reference)
//
#include <hip/hip_runtime.h>

// Problem constants
#define NSEQ   3200        // B*T
#define NROWS  80000       // B*T*V
#define VDIM   25
#define DDIM   128
#define NE     1024
#define ZQ_N   10240000    // NROWS*DDIM
#define IDX_OFF 10240001

__device__ __forceinline__ float dot4acc(float4 x, float4 w, float p) {
    p = fmaf(x.x, w.x, p);
    p = fmaf(x.y, w.y, p);
    p = fmaf(x.z, w.z, p);
    p = fmaf(x.w, w.w, p);
    return p;
}

__global__ __launch_bounds__(256) void k_init(float* loss_part) {
    int i = blockIdx.x * 256 + threadIdx.x;
    if (i < 1024) loss_part[i] = 0.f;
}

// wsq[q*1024+j] = sum_d emb[q][j][d]^2   (4096 rows total)
__global__ __launch_bounds__(256) void k_wsq(const float* __restrict__ emb,
                                             float* __restrict__ wsq) {
    int t = threadIdx.x;
    int row = blockIdx.x * 64 + (t >> 2);
    int seg = t & 3;
    const float4* p = (const float4*)(emb + row * 128 + seg * 32);
    float a = 0.f;
#pragma unroll
    for (int i = 0; i < 8; i++) {
        float4 w = p[i];
        a = fmaf(w.x, w.x, a); a = fmaf(w.y, w.y, a);
        a = fmaf(w.z, w.z, a); a = fmaf(w.w, w.w, a);
    }
    a += __shfl_xor(a, 1);
    a += __shfl_xor(a, 2);
    if (seg == 0) wsq[row] = a;
}

// One block per sequence n: ring-GCN + linear + LeakyReLU + LN + residual add.
// Writes refined[n] and s[row]=||refined_row||^2.
__global__ __launch_bounds__(256) void k_refine(const float* __restrict__ src,
        float* __restrict__ refined, float* __restrict__ s_out,
        const float* __restrict__ An, const float* __restrict__ gw,
        const float* __restrict__ gb, const float* __restrict__ lsc,
        const float* __restrict__ lbi) {
    __shared__ __align__(16) float Rn[25 * 128];
    __shared__ __align__(16) float nei[32 * 132];
    __shared__ float Al[625];
    const int tid = threadIdx.x;
    const int n = blockIdx.x;

    const float4* sp = (const float4*)(src + n * 3200);
    float4* Rn4 = (float4*)Rn;
    for (int i = tid; i < 800; i += 256) Rn4[i] = sp[i];
    for (int i = tid; i < 625; i += 256) Al[i] = An[i];
    __syncthreads();

    // neigh[v][d] = sum of 3 ring taps (A_norm values read from input)
    for (int i = tid; i < 3200; i += 256) {
        int v = i >> 7, d = i & 127;
        int vm = (v == 0) ? 24 : v - 1;
        int vp = (v == 24) ? 0 : v + 1;
        float val = Al[v * 25 + vm] * Rn[vm * 128 + d];
        val = fmaf(Al[v * 25 + v],  Rn[v  * 128 + d], val);
        val = fmaf(Al[v * 25 + vp], Rn[vp * 128 + d], val);
        nei[v * 132 + d] = val;
    }
    for (int i = tid; i < 7 * 132; i += 256) nei[25 * 132 + i] = 0.f;
    __syncthreads();

    // linear: y[v][dp] = sum_d nei[v][d]*gw[dp][d]
    const int jl = tid & 31, vg = tid >> 5;
    const int dp0 = jl * 4, v0 = vg * 4;
    float acc[4][4];
#pragma unroll
    for (int a = 0; a < 4; a++)
#pragma unroll
        for (int b = 0; b < 4; b++) acc[a][b] = 0.f;

#pragma unroll 4
    for (int k = 0; k < 128; k += 4) {
        float4 w0 = *(const float4*)(gw + (dp0 + 0) * 128 + k);
        float4 w1 = *(const float4*)(gw + (dp0 + 1) * 128 + k);
        float4 w2 = *(const float4*)(gw + (dp0 + 2) * 128 + k);
        float4 w3 = *(const float4*)(gw + (dp0 + 3) * 128 + k);
#pragma unroll
        for (int vv = 0; vv < 4; vv++) {
            float4 x = *(const float4*)(&nei[(v0 + vv) * 132 + k]);
            acc[vv][0] = dot4acc(x, w0, acc[vv][0]);
            acc[vv][1] = dot4acc(x, w1, acc[vv][1]);
            acc[vv][2] = dot4acc(x, w2, acc[vv][2]);
            acc[vv][3] = dot4acc(x, w3, acc[vv][3]);
        }
    }

    float4 b4  = *(const float4*)(gb + dp0);
    float4 sc4 = *(const float4*)(lsc + dp0);
    float4 bi4 = *(const float4*)(lbi + dp0);
    const float bb[4] = {b4.x, b4.y, b4.z, b4.w};
    const float sc[4] = {sc4.x, sc4.y, sc4.z, sc4.w};
    const float bi[4] = {bi4.x, bi4.y, bi4.z, bi4.w};

#pragma unroll
    for (int vv = 0; vv < 4; vv++) {
        int v = v0 + vv;
        if (v >= 25) break;   // uniform within each 32-lane group
        float y[4];
#pragma unroll
        for (int c = 0; c < 4; c++) {
            float t = acc[vv][c] + bb[c];
            y[c] = (t >= 0.f) ? t : 0.2f * t;   // LeakyReLU(0.2)
        }
        float s1 = y[0] + y[1] + y[2] + y[3];
#pragma unroll
        for (int m = 1; m <= 16; m <<= 1) s1 += __shfl_xor(s1, m);
        float mu = s1 * (1.f / 128.f);
        float d2 = 0.f;
#pragma unroll
        for (int c = 0; c < 4; c++) { float t = y[c] - mu; d2 = fmaf(t, t, d2); }
#pragma unroll
        for (int m = 1; m <= 16; m <<= 1) d2 += __shfl_xor(d2, m);
        float inv = 1.f / sqrtf(d2 * (1.f / 128.f) + 1e-5f);

        float4 rn4 = *(const float4*)(&Rn[v * 128 + dp0]);
        const float rn[4] = {rn4.x, rn4.y, rn4.z, rn4.w};
        float o[4];
#pragma unroll
        for (int c = 0; c < 4; c++)
            o[c] = rn[c] + 0.1f * ((y[c] - mu) * inv * sc[c] + bi[c]);

        *(float4*)(refined + (n * 25 + v) * 128 + dp0) =
            make_float4(o[0], o[1], o[2], o[3]);

        float ss = 0.f;
#pragma unroll
        for (int c = 0; c < 4; c++) ss = fmaf(o[c], o[c], ss);
#pragma unroll
        for (int m = 1; m <= 16; m <<= 1) ss += __shfl_xor(ss, m);
        if (jl == 0) s_out[n * 25 + v] = ss;
    }
}

// Fused distance-GEMM + argmin + quantizer update. 64 rows/block.
__global__ __launch_bounds__(256) void k_vq(const float* __restrict__ refined,
        const float* __restrict__ emb_k, const float* __restrict__ wsq_k,
        const float* __restrict__ s_g, const float* res_src, float* res_dst,
        float* zq, float* __restrict__ idx_out, float* __restrict__ loss_part,
        int stage) {
    __shared__ __align__(16) float xl[64 * 132];
    __shared__ __align__(16) float wl[1024];
    __shared__ int il[64];
    const int tid = threadIdx.x;
    const int row0 = blockIdx.x * 64;

    // stage x rows into LDS (row-major, stride 132: 16B-aligned, conflict-light)
    for (int q = tid; q < 2048; q += 256) {
        int r = q >> 5, kq = q & 31;
        float4 t = *(const float4*)(refined + (row0 + r) * 128 + kq * 4);
        *(float4*)(&xl[r * 132 + kq * 4]) = t;
    }
    ((float4*)wl)[tid] = ((const float4*)wsq_k)[tid];

    const int jl = tid & 15, rg = tid >> 4;
    const int r0 = rg * 4;
    float4 s4 = *(const float4*)(s_g + row0 + r0);
    const float sv[4] = {s4.x, s4.y, s4.z, s4.w};
    __syncthreads();

    float minv[4] = {3.402823466e38f, 3.402823466e38f, 3.402823466e38f, 3.402823466e38f};
    int   mini[4] = {0, 0, 0, 0};

    for (int c = 0; c < 16; c++) {
        const int j0 = c * 64 + jl * 4;
        const float* wp = emb_k + j0 * 128;
        float p[4][4];
#pragma unroll
        for (int a = 0; a < 4; a++)
#pragma unroll
            for (int b = 0; b < 4; b++) p[a][b] = 0.f;

#pragma unroll 4
        for (int k = 0; k < 128; k += 4) {
            float4 w0 = *(const float4*)(wp + k);
            float4 w1 = *(const float4*)(wp + 128 + k);
            float4 w2 = *(const float4*)(wp + 256 + k);
            float4 w3 = *(const float4*)(wp + 384 + k);
#pragma unroll
            for (int rr = 0; rr < 4; rr++) {
                float4 x = *(const float4*)(&xl[(r0 + rr) * 132 + k]);
                p[rr][0] = dot4acc(x, w0, p[rr][0]);
                p[rr][1] = dot4acc(x, w1, p[rr][1]);
                p[rr][2] = dot4acc(x, w2, p[rr][2]);
                p[rr][3] = dot4acc(x, w3, p[rr][3]);
            }
        }
        float4 wq = *(const float4*)(&wl[j0]);
        const float wqa[4] = {wq.x, wq.y, wq.z, wq.w};
#pragma unroll
        for (int rr = 0; rr < 4; rr++)
#pragma unroll
            for (int cc = 0; cc < 4; cc++) {
                // exact reference formula order: (||x||^2 - 2p) + ||w||^2
                float dist = (sv[rr] - 2.0f * p[rr][cc]) + wqa[cc];
                if (dist < minv[rr]) { minv[rr] = dist; mini[rr] = j0 + cc; }
            }
    }

    // reduce argmin across the 16 col-lanes; ties -> smaller index (np.argmin)
#pragma unroll
    for (int rr = 0; rr < 4; rr++) {
#pragma unroll
        for (int m = 1; m <= 8; m <<= 1) {
            float ov = __shfl_xor(minv[rr], m);
            int   oi = __shfl_xor(mini[rr], m);
            if (ov < minv[rr] || (ov == minv[rr] && oi < mini[rr])) {
                minv[rr] = ov; mini[rr] = oi;
            }
        }
        if (jl == 0) {
            il[r0 + rr] = mini[rr];
            idx_out[(row0 + r0 + rr) * 4 + stage] = (float)mini[rr];
        }
    }
    __syncthreads();

    // update: q = W[idx]; loss += ||q - res||^2; res -= q; cum += q
    const int r = tid >> 2, seg = tid & 3;
    const int row = row0 + r;
    const int idx = il[r];
    const float4* qp = (const float4*)(emb_k + idx * 128 + seg * 32);
    const float4* rp = (const float4*)(res_src + row * 128 + seg * 32);
    float4* rw = (float4*)(res_dst + row * 128 + seg * 32);
    float4* zp = (float4*)(zq + row * 128 + seg * 32);
    float acc = 0.f;
#pragma unroll
    for (int i = 0; i < 8; i++) {
        float4 q4 = qp[i];
        float4 r4 = rp[i];
        float dx = q4.x - r4.x, dy = q4.y - r4.y, dz = q4.z - r4.z, dw = q4.w - r4.w;
        acc = fmaf(dx, dx, acc); acc = fmaf(dy, dy, acc);
        acc = fmaf(dz, dz, acc); acc = fmaf(dw, dw, acc);
        rw[i] = make_float4(r4.x - q4.x, r4.y - q4.y, r4.z - q4.z, r4.w - q4.w);
        if (stage == 0) {
            zp[i] = q4;
        } else {
            float4 z4 = zp[i];
            zp[i] = make_float4(z4.x + q4.x, z4.y + q4.y, z4.z + q4.z, z4.w + q4.w);
        }
    }
    acc += __shfl_xor(acc, 1);  acc += __shfl_xor(acc, 2);
    acc += __shfl_xor(acc, 4);  acc += __shfl_xor(acc, 8);
    acc += __shfl_xor(acc, 16); acc += __shfl_xor(acc, 32);
    if ((tid & 63) == 0) atomicAdd(&loss_part[blockIdx.x & 1023], acc);
}

__global__ __launch_bounds__(256) void k_loss(const float* __restrict__ loss_part,
                                              float* __restrict__ out) {
    int t = threadIdx.x;
    float a = loss_part[t] + loss_part[t + 256] + loss_part[t + 512] + loss_part[t + 768];
#pragma unroll
    for (int m = 1; m <= 32; m <<= 1) a += __shfl_xor(a, m);
    __shared__ float w[4];
    if ((t & 63) == 0) w[t >> 6] = a;
    __syncthreads();
    if (t == 0) {
        float s = w[0] + w[1] + w[2] + w[3];
        // (1+beta)/D mean over (n_q * N * V) elements
        out[ZQ_N] = s * (1.25f / (128.f * 320000.f));
    }
}

extern "C" void kernel_launch(void* const* d_in, const int* in_sizes, int n_in,
                              void* d_out, int out_size, void* d_ws, size_t ws_size,
                              hipStream_t stream) {
    (void)in_sizes; (void)n_in; (void)out_size; (void)ws_size;
    const float* z   = (const float*)d_in[0];
    const float* emb = (const float*)d_in[1];
    const float* An  = (const float*)d_in[2];
    const float* gw  = (const float*)d_in[3];
    const float* gb  = (const float*)d_in[4];
    const float* lsc = (const float*)d_in[5];
    const float* lbi = (const float*)d_in[6];

    float* out     = (float*)d_out;
    float* zq      = out;               // [0 .. 10,240,000)
    float* idx_out = out + IDX_OFF;     // [10,240,001 .. 10,560,001)

    float* ws        = (float*)d_ws;
    float* resbuf    = ws;                   // 10,240,000
    float* refined   = ws + 10240000;        // 10,240,000
    float* s_g       = ws + 20480000;        // 80,000
    float* wsq       = ws + 20560000;        // 4,096
    float* loss_part = ws + 20564096;        // 1,024

    k_init<<<4, 256, 0, stream>>>(loss_part);
    k_wsq<<<64, 256, 0, stream>>>(emb, wsq);
    for (int k = 0; k < 4; k++) {
        const float* src = (k == 0) ? z : resbuf;
        k_refine<<<3200, 256, 0, stream>>>(src, refined, s_g, An, gw, gb, lsc, lbi);
        k_vq<<<1250, 256, 0, stream>>>(refined, emb + k * 131072, wsq + k * 1024,
                                       s_g, src, resbuf, zq, idx_out, loss_part, k);
    }
    k_loss<<<1, 256, 0, stream>>>(loss_part, out);
}

// Round 2
// 1998.937 us; speedup vs baseline: 3.2961x; 3.2961x over previous
//
#include <hip/hip_runtime.h>

// Problem: B*T=3200 seqs, V=25, D=128, N_Q=4, N_E=1024. NROWS=80000.
// d_out: zq [10,240,000] | loss [1] | indices [320,000]
// d_ws needs >= 84.5 MB (21,105,792 floats).
#define ZQ_N    10240000
#define IDX_OFF 10240001
#define FLT_BIG 3.402823466e38f

__device__ __forceinline__ float getc(const float4& v, int k) {
    return k == 0 ? v.x : k == 1 ? v.y : k == 2 ? v.z : v.w;
}

__global__ __launch_bounds__(256) void k_init(float* loss_part) {
    int i = blockIdx.x * 256 + threadIdx.x;
    if (i < 1024) loss_part[i] = 0.f;
}

// wsq[q*1024+j] = ||emb[q][j]||^2
__global__ __launch_bounds__(256) void k_wsq(const float* __restrict__ emb,
                                             float* __restrict__ wsq) {
    int t = threadIdx.x;
    int row = blockIdx.x * 64 + (t >> 2);
    int seg = t & 3;
    const float4* p = (const float4*)(emb + row * 128 + seg * 32);
    float a = 0.f;
#pragma unroll
    for (int i = 0; i < 8; i++) {
        float4 w = p[i];
        a = fmaf(w.x, w.x, a); a = fmaf(w.y, w.y, a);
        a = fmaf(w.z, w.z, a); a = fmaf(w.w, w.w, a);
    }
    a += __shfl_xor(a, 1);
    a += __shfl_xor(a, 2);
    if (seg == 0) wsq[row] = a;
}

// dst[C][R] = src[R][C]^T, R,C multiples of 32. 256 threads, 32x32 LDS tile.
__global__ __launch_bounds__(256) void k_transpose(const float* __restrict__ src,
                                                   float* __restrict__ dst,
                                                   int R, int C) {
    __shared__ float t[32][33];
    const int tx = threadIdx.x & 31, ty = threadIdx.x >> 5;
    const int r0 = blockIdx.y * 32, c0 = blockIdx.x * 32;
#pragma unroll
    for (int i = 0; i < 4; i++)
        t[ty + 8 * i][tx] = src[(size_t)(r0 + ty + 8 * i) * C + c0 + tx];
    __syncthreads();
#pragma unroll
    for (int i = 0; i < 4; i++)
        dst[(size_t)(c0 + ty + 8 * i) * R + r0 + tx] = t[tx][ty + 8 * i];
}

// One block per sequence: ring-GCN + linear(gwT, coalesced) + LeakyReLU + LN + res add.
__global__ __launch_bounds__(256) void k_refine(const float* __restrict__ src,
        float* __restrict__ refined, float* __restrict__ s_out,
        const float* __restrict__ An, const float* __restrict__ gwT,
        const float* __restrict__ gb, const float* __restrict__ lsc,
        const float* __restrict__ lbi) {
    __shared__ __align__(16) float Rn[25 * 128];
    __shared__ __align__(16) float nei[32 * 132];   // rows 25..31 junk, discarded
    __shared__ float Al[625];
    const int tid = threadIdx.x;
    const int n = blockIdx.x;

    const float4* sp = (const float4*)(src + n * 3200);
    float4* Rn4 = (float4*)Rn;
    for (int i = tid; i < 800; i += 256) Rn4[i] = sp[i];
    for (int i = tid; i < 625; i += 256) Al[i] = An[i];
    __syncthreads();

    for (int i = tid; i < 3200; i += 256) {
        int v = i >> 7, d = i & 127;
        int vm = (v == 0) ? 24 : v - 1;
        int vp = (v == 24) ? 0 : v + 1;
        float val = Al[v * 25 + vm] * Rn[vm * 128 + d];
        val = fmaf(Al[v * 25 + v],  Rn[v  * 128 + d], val);
        val = fmaf(Al[v * 25 + vp], Rn[vp * 128 + d], val);
        nei[v * 132 + d] = val;
    }
    __syncthreads();

    const int dpg = tid & 31;     // 32 col-groups of 4 dp
    const int vs  = tid >> 5;     // 8 row slots; rows vs, vs+8, vs+16, vs+24
    const int dp0 = dpg * 4;

    float acc[4][4];
#pragma unroll
    for (int a = 0; a < 4; a++)
#pragma unroll
        for (int b = 0; b < 4; b++) acc[a][b] = 0.f;

    for (int kg = 0; kg < 128; kg += 4) {
        float4 xv[4];
#pragma unroll
        for (int i = 0; i < 4; i++)
            xv[i] = *(const float4*)(&nei[(vs + 8 * i) * 132 + kg]);
#pragma unroll
        for (int kk = 0; kk < 4; kk++) {
            float4 w = *(const float4*)(gwT + (kg + kk) * 128 + dp0);
#pragma unroll
            for (int i = 0; i < 4; i++) {
                float xs = getc(xv[i], kk);
                acc[i][0] = fmaf(xs, w.x, acc[i][0]);
                acc[i][1] = fmaf(xs, w.y, acc[i][1]);
                acc[i][2] = fmaf(xs, w.z, acc[i][2]);
                acc[i][3] = fmaf(xs, w.w, acc[i][3]);
            }
        }
    }

    float4 b4  = *(const float4*)(gb + dp0);
    float4 sc4 = *(const float4*)(lsc + dp0);
    float4 bi4 = *(const float4*)(lbi + dp0);
    const float bb[4] = {b4.x, b4.y, b4.z, b4.w};
    const float sc[4] = {sc4.x, sc4.y, sc4.z, sc4.w};
    const float bi[4] = {bi4.x, bi4.y, bi4.z, bi4.w};

#pragma unroll
    for (int i = 0; i < 4; i++) {
        int v = vs + 8 * i;
        if (v >= 25) break;       // uniform within each 32-lane group
        float y[4];
#pragma unroll
        for (int c = 0; c < 4; c++) {
            float t = acc[i][c] + bb[c];
            y[c] = (t >= 0.f) ? t : 0.2f * t;       // LeakyReLU(0.2)
        }
        float s1 = y[0] + y[1] + y[2] + y[3];
#pragma unroll
        for (int m = 1; m <= 16; m <<= 1) s1 += __shfl_xor(s1, m);
        float mu = s1 * (1.f / 128.f);
        float d2 = 0.f;
#pragma unroll
        for (int c = 0; c < 4; c++) { float t = y[c] - mu; d2 = fmaf(t, t, d2); }
#pragma unroll
        for (int m = 1; m <= 16; m <<= 1) d2 += __shfl_xor(d2, m);
        float inv = 1.f / sqrtf(d2 * (1.f / 128.f) + 1e-5f);

        float4 rn4 = *(const float4*)(&Rn[v * 128 + dp0]);
        const float rn[4] = {rn4.x, rn4.y, rn4.z, rn4.w};
        float o[4];
#pragma unroll
        for (int c = 0; c < 4; c++)
            o[c] = rn[c] + 0.1f * ((y[c] - mu) * inv * sc[c] + bi[c]);

        *(float4*)(refined + (n * 25 + v) * 128 + dp0) =
            make_float4(o[0], o[1], o[2], o[3]);

        float ss = 0.f;
#pragma unroll
        for (int c = 0; c < 4; c++) ss = fmaf(o[c], o[c], ss);
#pragma unroll
        for (int m = 1; m <= 16; m <<= 1) ss += __shfl_xor(ss, m);
        if (dpg == 0) s_out[n * 25 + v] = ss;
    }
}

// Distance GEMM (X-LDS x coalesced global wT) + exact argmin + update. 64 rows/block.
__global__ __launch_bounds__(256) void k_vq(const float* __restrict__ refined,
        const float* __restrict__ wT,      // [128][4096] k-major, all 4 stages
        const float* __restrict__ emb_k,   // original [1024][128] for gather
        const float* __restrict__ wsq_k, const float* __restrict__ s_g,
        const float* res_src, float* res_dst, float* zq,
        float* __restrict__ idx_out, float* __restrict__ loss_part, int stage) {
    __shared__ __align__(16) float xl[64 * 132];    // 33792 B, stride-132 pad
    __shared__ float redv[16][64];
    __shared__ int   redi[16][64];
    __shared__ int   il[64];
    const int tid = threadIdx.x;
    const int row0 = blockIdx.x * 64;
    const int rg = tid & 15;       // rows rg, rg+16, rg+32, rg+48
    const int cg = tid >> 4;       // 16 col-groups

    for (int q = tid; q < 2048; q += 256) {
        int r = q >> 5, kq = (q & 31) * 4;
        *(float4*)(&xl[r * 132 + kq]) = *(const float4*)(refined + (row0 + r) * 128 + kq);
    }
    __syncthreads();

    float sv[4];
#pragma unroll
    for (int rr = 0; rr < 4; rr++) sv[rr] = s_g[row0 + rg + 16 * rr];

    float bestv[4] = {FLT_BIG, FLT_BIG, FLT_BIG, FLT_BIG};
    int   besti[4] = {0, 0, 0, 0};

    const float* wbase = wT + stage * 1024;
    for (int cb = 0; cb < 8; cb++) {
        const int jA = cb * 128 + cg * 4;
        const int jB = jA + 64;
        const float* wp = wbase + jA;   // + k*4096 ; +64 for B group
        float acc[4][8];
#pragma unroll
        for (int a = 0; a < 4; a++)
#pragma unroll
            for (int b = 0; b < 8; b++) acc[a][b] = 0.f;

        for (int kg = 0; kg < 128; kg += 4) {
            float4 xv0 = *(const float4*)(&xl[(rg     ) * 132 + kg]);
            float4 xv1 = *(const float4*)(&xl[(rg + 16) * 132 + kg]);
            float4 xv2 = *(const float4*)(&xl[(rg + 32) * 132 + kg]);
            float4 xv3 = *(const float4*)(&xl[(rg + 48) * 132 + kg]);
#pragma unroll
            for (int kk = 0; kk < 4; kk++) {
                float4 wA = *(const float4*)(wp + (kg + kk) * 4096);
                float4 wB = *(const float4*)(wp + (kg + kk) * 4096 + 64);
                float x0 = getc(xv0, kk), x1 = getc(xv1, kk);
                float x2 = getc(xv2, kk), x3 = getc(xv3, kk);
                acc[0][0] = fmaf(x0, wA.x, acc[0][0]);
                acc[0][1] = fmaf(x0, wA.y, acc[0][1]);
                acc[0][2] = fmaf(x0, wA.z, acc[0][2]);
                acc[0][3] = fmaf(x0, wA.w, acc[0][3]);
                acc[0][4] = fmaf(x0, wB.x, acc[0][4]);
                acc[0][5] = fmaf(x0, wB.y, acc[0][5]);
                acc[0][6] = fmaf(x0, wB.z, acc[0][6]);
                acc[0][7] = fmaf(x0, wB.w, acc[0][7]);
                acc[1][0] = fmaf(x1, wA.x, acc[1][0]);
                acc[1][1] = fmaf(x1, wA.y, acc[1][1]);
                acc[1][2] = fmaf(x1, wA.z, acc[1][2]);
                acc[1][3] = fmaf(x1, wA.w, acc[1][3]);
                acc[1][4] = fmaf(x1, wB.x, acc[1][4]);
                acc[1][5] = fmaf(x1, wB.y, acc[1][5]);
                acc[1][6] = fmaf(x1, wB.z, acc[1][6]);
                acc[1][7] = fmaf(x1, wB.w, acc[1][7]);
                acc[2][0] = fmaf(x2, wA.x, acc[2][0]);
                acc[2][1] = fmaf(x2, wA.y, acc[2][1]);
                acc[2][2] = fmaf(x2, wA.z, acc[2][2]);
                acc[2][3] = fmaf(x2, wA.w, acc[2][3]);
                acc[2][4] = fmaf(x2, wB.x, acc[2][4]);
                acc[2][5] = fmaf(x2, wB.y, acc[2][5]);
                acc[2][6] = fmaf(x2, wB.z, acc[2][6]);
                acc[2][7] = fmaf(x2, wB.w, acc[2][7]);
                acc[3][0] = fmaf(x3, wA.x, acc[3][0]);
                acc[3][1] = fmaf(x3, wA.y, acc[3][1]);
                acc[3][2] = fmaf(x3, wA.z, acc[3][2]);
                acc[3][3] = fmaf(x3, wA.w, acc[3][3]);
                acc[3][4] = fmaf(x3, wB.x, acc[3][4]);
                acc[3][5] = fmaf(x3, wB.y, acc[3][5]);
                acc[3][6] = fmaf(x3, wB.z, acc[3][6]);
                acc[3][7] = fmaf(x3, wB.w, acc[3][7]);
            }
        }

#pragma unroll
        for (int c = 0; c < 4; c++) {
            float wqA = wsq_k[jA + c];
            float wqB = wsq_k[jB + c];
#pragma unroll
            for (int rr = 0; rr < 4; rr++) {
                float dA = (sv[rr] - 2.0f * acc[rr][c]) + wqA;
                if (dA < bestv[rr] || (dA == bestv[rr] && jA + c < besti[rr])) {
                    bestv[rr] = dA; besti[rr] = jA + c;
                }
                float dB = (sv[rr] - 2.0f * acc[rr][c + 4]) + wqB;
                if (dB < bestv[rr] || (dB == bestv[rr] && jB + c < besti[rr])) {
                    bestv[rr] = dB; besti[rr] = jB + c;
                }
            }
        }
    }

#pragma unroll
    for (int rr = 0; rr < 4; rr++) {
        redv[cg][rg + 16 * rr] = bestv[rr];
        redi[cg][rg + 16 * rr] = besti[rr];
    }
    __syncthreads();
    if (tid < 64) {
        float bv = redv[0][tid]; int bi = redi[0][tid];
#pragma unroll
        for (int c = 1; c < 16; c++) {
            float v = redv[c][tid]; int i2 = redi[c][tid];
            if (v < bv || (v == bv && i2 < bi)) { bv = v; bi = i2; }
        }
        il[tid] = bi;
        idx_out[(row0 + tid) * 4 + stage] = (float)bi;
    }
    __syncthreads();

    // update: q = W[idx]; loss += ||q - res||^2; res -= q; cum += q
    const int r = tid >> 2, seg = tid & 3;
    const int row = row0 + r;
    const int idx = il[r];
    const float4* qp = (const float4*)(emb_k + idx * 128 + seg * 32);
    const float4* rp = (const float4*)(res_src + row * 128 + seg * 32);
    float4* rw = (float4*)(res_dst + row * 128 + seg * 32);
    float4* zp = (float4*)(zq + row * 128 + seg * 32);
    float acc = 0.f;
#pragma unroll
    for (int i = 0; i < 8; i++) {
        float4 q4 = qp[i];
        float4 r4 = rp[i];
        float dx = q4.x - r4.x, dy = q4.y - r4.y, dz = q4.z - r4.z, dw = q4.w - r4.w;
        acc = fmaf(dx, dx, acc); acc = fmaf(dy, dy, acc);
        acc = fmaf(dz, dz, acc); acc = fmaf(dw, dw, acc);
        rw[i] = make_float4(r4.x - q4.x, r4.y - q4.y, r4.z - q4.z, r4.w - q4.w);
        if (stage == 0) {
            zp[i] = q4;
        } else {
            float4 z4 = zp[i];
            zp[i] = make_float4(z4.x + q4.x, z4.y + q4.y, z4.z + q4.z, z4.w + q4.w);
        }
    }
    acc += __shfl_xor(acc, 1);  acc += __shfl_xor(acc, 2);
    acc += __shfl_xor(acc, 4);  acc += __shfl_xor(acc, 8);
    acc += __shfl_xor(acc, 16); acc += __shfl_xor(acc, 32);
    if ((tid & 63) == 0) atomicAdd(&loss_part[blockIdx.x & 1023], acc);
}

__global__ __launch_bounds__(256) void k_loss(const float* __restrict__ loss_part,
                                              float* __restrict__ out) {
    int t = threadIdx.x;
    float a = loss_part[t] + loss_part[t + 256] + loss_part[t + 512] + loss_part[t + 768];
#pragma unroll
    for (int m = 1; m <= 32; m <<= 1) a += __shfl_xor(a, m);
    __shared__ float w[4];
    if ((t & 63) == 0) w[t >> 6] = a;
    __syncthreads();
    if (t == 0) {
        float s = w[0] + w[1] + w[2] + w[3];
        out[ZQ_N] = s * (1.25f / (128.f * 320000.f));
    }
}

extern "C" void kernel_launch(void* const* d_in, const int* in_sizes, int n_in,
                              void* d_out, int out_size, void* d_ws, size_t ws_size,
                              hipStream_t stream) {
    (void)in_sizes; (void)n_in; (void)out_size; (void)ws_size;
    const float* z   = (const float*)d_in[0];
    const float* emb = (const float*)d_in[1];
    const float* An  = (const float*)d_in[2];
    const float* gw  = (const float*)d_in[3];
    const float* gb  = (const float*)d_in[4];
    const float* lsc = (const float*)d_in[5];
    const float* lbi = (const float*)d_in[6];

    float* out     = (float*)d_out;
    float* zq      = out;
    float* idx_out = out + IDX_OFF;

    float* ws        = (float*)d_ws;
    float* resbuf    = ws;                   // 10,240,000
    float* refined   = ws + 10240000;        // 10,240,000
    float* wT        = ws + 20480000;        // 524,288  [128][4096]
    float* gwT       = ws + 21004288;        // 16,384   [128][128]
    float* s_g       = ws + 21020672;        // 80,000
    float* wsq       = ws + 21100672;        // 4,096
    float* loss_part = ws + 21104768;        // 1,024   (end: 21,105,792 floats)

    k_init<<<4, 256, 0, stream>>>(loss_part);
    k_wsq<<<64, 256, 0, stream>>>(emb, wsq);
    k_transpose<<<dim3(4, 128), 256, 0, stream>>>(emb, wT, 4096, 128);
    k_transpose<<<dim3(4, 4), 256, 0, stream>>>(gw, gwT, 128, 128);
    for (int k = 0; k < 4; k++) {
        const float* src = (k == 0) ? z : resbuf;
        k_refine<<<3200, 256, 0, stream>>>(src, refined, s_g, An, gwT, gb, lsc, lbi);
        k_vq<<<1250, 256, 0, stream>>>(refined, wT, emb + k * 131072, wsq + k * 1024,
                                       s_g, src, resbuf, zq, idx_out, loss_part, k);
    }
    k_loss<<<1, 256, 0, stream>>>(loss_part, out);
}